// Round 8
// baseline (140.579 us; speedup 1.0000x reference)
//
#include <hip/hip_runtime.h>
#include <hip/hip_fp16.h>
#include <hip/hip_cooperative_groups.h>
#include <math.h>

namespace cg = cooperative_groups;

#define N_ATOMS 2048
#define NSP 7
#define AEVD 112      // real radial features; padded to 128 (K-tile) only in LDS
#define MTILE 16      // atoms per MLP block (full 16-row M-tile)
#define NBLK_MLP 135  // max tiles: 2048/16 + 7 slack
#define AEV_TASKS (N_ATOMS * NSP)           // (atom, species) wave-tasks, 16 shells each
#define AEV_BLKS (AEV_TASKS / 4)            // fallback: 3584 blocks of 4 waves
#define MEGA_GRID 448                       // 448 blk x 4 waves x 8 tasks = 14336

typedef __attribute__((ext_vector_type(8))) short short8;
typedef __attribute__((ext_vector_type(4))) float f32x4;
typedef __attribute__((ext_vector_type(2))) float f32x2;
typedef unsigned short ushort_t;

// ---- guaranteed-native transcendentals (single HW instruction) ----
#if !__has_builtin(__builtin_amdgcn_exp2f)
extern "C" __device__ float __ocml_native_exp2_f32(float);
#endif
#if !__has_builtin(__builtin_amdgcn_cosf)
extern "C" __device__ float __ocml_native_cos_f32(float);
#endif
#if !__has_builtin(__builtin_amdgcn_sqrtf)
extern "C" __device__ float __ocml_native_sqrt_f32(float);
#endif

__device__ __forceinline__ float nexp2(float x) {       // 2^x  (v_exp_f32)
#if __has_builtin(__builtin_amdgcn_exp2f)
    return __builtin_amdgcn_exp2f(x);
#else
    return __ocml_native_exp2_f32(x);
#endif
}
__device__ __forceinline__ float ncos_rev(float x) {    // cos(2*pi*x) (v_cos_f32)
#if __has_builtin(__builtin_amdgcn_cosf)
    return __builtin_amdgcn_cosf(x);
#else
    return __ocml_native_cos_f32(x * 6.2831853071795865f);
#endif
}
__device__ __forceinline__ float nsqrt(float x) {       // sqrt(x) (v_sqrt_f32)
#if __has_builtin(__builtin_amdgcn_sqrtf)
    return __builtin_amdgcn_sqrtf(x);
#else
    return __ocml_native_sqrt_f32(x);
#endif
}

// even-shell mus (ladder order; SHFR[2j] = mu_e[j])
__device__ __constant__ float c_mue[8] = {0.9f, 1.43f, 1.96f, 2.49f,
                                          3.02f, 3.55f, 4.08f, 4.61f};

#define CS_LOG2E  (-23.083120654223414f)   // -16*log2(e)
#define CB_LOG2E  ( 46.166241308446828f)   // +32*log2(e)
#define EA_COEF   ( 12.003222740196175f)   // CB_LOG2E * 0.26 (even->odd shell step)
#define EB_COEF   ( 24.468107893476819f)   // CB_LOG2E * 0.53 (even->even shell step)

__device__ __forceinline__ float celu01(float x) {
    return x > 0.f ? x : 0.1f * (nexp2(x * 14.426950f) - 1.f);
}

__device__ __forceinline__ ushort_t f2bf(float v) {   // RNE fp32->bf16
    unsigned u = __float_as_uint(v);
    u += 0x7fffu + ((u >> 16) & 1u);
    return (ushort_t)(u >> 16);
}

__device__ __forceinline__ unsigned pkadd16(unsigned a, unsigned b) {  // v_pk_add_f16
    __half2 x, y;
    __builtin_memcpy(&x, &a, 4);
    __builtin_memcpy(&y, &b, 4);
    __half2 r = __hadd2(x, y);
    unsigned u;
    __builtin_memcpy(&u, &r, 4);
    return u;
}

#define PREP_G0 28672   // 7*16*4*64
#define PREP_G1 43008   // 7*12*8*64
#define PREP_G2 26880   // 7*10*6*64
#define PREP_GT (PREP_G0 + PREP_G1 + PREP_G2)   // 98560 = 385*256

// ---------------------------------------------------------------------------
// shared helpers (used by mega kernel and fallback kernels)
// ---------------------------------------------------------------------------
__device__ __forceinline__ void repack_unit(
    int g, const float* __restrict__ W0, const float* __restrict__ W1,
    const float* __restrict__ W2,
    ushort_t* __restrict__ wr0, ushort_t* __restrict__ wr1,
    ushort_t* __restrict__ wr2)
{
    const float* W; ushort_t* dst; int NT, KS, KREAL, KIN, NOUT;
    if (g < PREP_G0)                 { W = W0; dst = wr0; NT = 16; KS = 4; KREAL = 112; KIN = 1008; NOUT = 256; }
    else if (g < PREP_G0 + PREP_G1)  { g -= PREP_G0; W = W1; dst = wr1; NT = 12; KS = 8; KREAL = 256; KIN = 256; NOUT = 192; }
    else                             { g -= PREP_G0 + PREP_G1; W = W2; dst = wr2; NT = 10; KS = 6; KREAL = 192; KIN = 192; NOUT = 160; }
    int L = g & 63, rest = g >> 6;
    int ks = rest % KS; rest /= KS;
    int nt = rest % NT; int s = rest / NT;
    int n = nt * 16 + (L & 15);
    int k0 = ks * 32 + ((L >> 4) << 3);
    const float* src = W + (size_t)s * KIN * NOUT + n;
    short8 v8;
#pragma unroll
    for (int j = 0; j < 8; ++j) {
        int k = k0 + j;
        float v = (k < KREAL) ? src[(size_t)k * NOUT] : 0.f;
        v8[j] = (short)f2bf(v);
    }
    *(short8*)(dst + (size_t)g * 8) = v8;   // LOCAL g (fragment-linear)
}

// AEV per-task body (prologue constants passed in; one (atom,species) task)
__device__ __forceinline__ void aev_task(
    int gid, int jl, const int* __restrict__ seg,
    const float4* __restrict__ cxyz, ushort_t* __restrict__ aevb,
    f32x2 cke0, f32x2 cke1, f32x2 cke2, const float* cko)
{
    int atom = gid / 7;                    // magic-mul const div
    int s = gid - atom * 7;

    const float BE_A0 = CB_LOG2E * 0.9f;
    const float GE_A0 = CS_LOG2E * (0.9f * 0.9f);
    const float BE_A1 = CB_LOG2E * 3.02f;
    const float GE_A1 = CS_LOG2E * (3.02f * 3.02f);

    float4 ci = cxyz[atom];
    float xi = ci.x, yi = ci.y, zi = ci.z;
    int pb = seg[s], pe = seg[s + 1];

    f32x2 accE[4], accO[4];
#pragma unroll
    for (int i = 0; i < 4; ++i) {
        accE[i] = (f32x2){0.f, 0.f};
        accO[i] = (f32x2){0.f, 0.f};
    }

    const float4* pj = cxyz + pb + jl;
    for (int n = pe - pb - jl; n > 0; n -= 64, pj += 64) {
        float4 cj = *pj;
        float dx = cj.x - xi, dy = cj.y - yi, dz = cj.z - zi;
        float sq = fmaf(dx, dx, fmaf(dy, dy, dz * dz));
        float d  = nsqrt(sq);
        float dc = fminf(d, 5.2f);
        float fc = fmaf(0.5f, ncos_rev(dc * 0.09615384615f), 0.5f);
        float uc = CS_LOG2E * sq;
        float ea = nexp2(dc * EA_COEF);
        float fe = ea * fc;
        float ebv = nexp2(dc * EB_COEF);
        f32x2 eb2 = (f32x2){ebv, ebv};
        f32x2 fc2 = (f32x2){fc, fc};
        f32x2 fe2 = (f32x2){fe, fe};
        f32x2 ek0 = eb2 * cke0;
        f32x2 ek1 = eb2 * cke1;
        f32x2 ek2 = eb2 * cke2;
        f32x2 ve = (f32x2){ nexp2(fmaf(dc, BE_A0, uc) + GE_A0),
                            nexp2(fmaf(dc, BE_A1, uc) + GE_A1) };
        accE[0] = ve * fc2 + accE[0];  accO[0] = ve * fe2 + accO[0];
        ve = ve * ek0;
        accE[1] = ve * fc2 + accE[1];  accO[1] = ve * fe2 + accO[1];
        ve = ve * ek1;
        accE[2] = ve * fc2 + accE[2];  accO[2] = ve * fe2 + accO[2];
        ve = ve * ek2;
        accE[3] = ve * fc2 + accE[3];  accO[3] = ve * fe2 + accO[3];
    }

    if (pb <= atom && atom < pe && ((atom - pb) & 63) == jl) {
        f32x2 ve = (f32x2){ nexp2(GE_A0), nexp2(GE_A1) };
        accE[0] -= ve;  accO[0] -= ve;
        ve = ve * cke0;
        accE[1] -= ve;  accO[1] -= ve;
        ve = ve * cke1;
        accE[2] -= ve;  accO[2] -= ve;
        ve = ve * cke2;
        accE[3] -= ve;  accO[3] -= ve;
    }

    unsigned hu[8];
#pragma unroll
    for (int j = 0; j < 8; ++j) {
        float E = (j < 4) ? accE[j][0] : accE[j - 4][1];
        float O = ((j < 4) ? accO[j][0] : accO[j - 4][1]) * cko[j];
        __half2 hh = __floats2half2_rn(E, O);
        __builtin_memcpy(&hu[j], &hh, 4);
    }

    bool hi5 = (jl & 32) != 0;
#pragma unroll
    for (int j = 0; j < 4; ++j) {
        unsigned snd = hi5 ? hu[j] : hu[j + 4];
        unsigned rcv = (unsigned)__shfl_xor((int)snd, 32);
        unsigned kp  = hi5 ? hu[j + 4] : hu[j];
        hu[j] = pkadd16(kp, rcv);
    }
    bool hi4 = (jl & 16) != 0;
#pragma unroll
    for (int j = 0; j < 2; ++j) {
        unsigned snd = hi4 ? hu[j] : hu[j + 2];
        unsigned rcv = (unsigned)__shfl_xor((int)snd, 16);
        unsigned kp  = hi4 ? hu[j + 2] : hu[j];
        hu[j] = pkadd16(kp, rcv);
    }
    bool hi3 = (jl & 8) != 0;
    {
        unsigned snd = hi3 ? hu[0] : hu[1];
        unsigned rcv = (unsigned)__shfl_xor((int)snd, 8);
        unsigned kp  = hi3 ? hu[1] : hu[0];
        hu[0] = pkadd16(kp, rcv);
    }
#pragma unroll
    for (int off = 4; off; off >>= 1)
        hu[0] = pkadd16(hu[0], (unsigned)__shfl_xor((int)hu[0], off));

    if ((jl & 7) == 0) {
        int w = jl >> 3;
        __half2 hv;
        __builtin_memcpy(&hv, &hu[0], 4);
        float2 f = __half22float2(hv);
        unsigned pk = (unsigned)f2bf(f.x) | ((unsigned)f2bf(f.y) << 16);
        *(unsigned*)(aevb + (size_t)atom * AEVD + s * 16 + 2 * w) = pk;
    }
}

// MLP layer for 4-wave (256-thread) blocks; wave-stride 4 over N-tiles.
template<int KSTEPS, int NT, int SIN, int NOUT, bool OUTF32>
__device__ __forceinline__ void compute_layer4(
    const ushort_t* __restrict__ wrep, const float* __restrict__ bias,
    const ushort_t* Ain, ushort_t* Aout, float* Fout, int lane, int wv)
{
    constexpr int MAXNT = (NT + 3) / 4;
    const int myNT = (NT - wv + 3) / 4;
    short8 wf[MAXNT][KSTEPS];
#pragma unroll
    for (int i = 0; i < MAXNT; ++i) {
        if (i < myNT) {
            int nt = wv + i * 4;
            const ushort_t* wb = wrep + ((size_t)nt * KSTEPS) * 512 + lane * 8;
#pragma unroll
            for (int ks = 0; ks < KSTEPS; ++ks)
                wf[i][ks] = *(const short8*)(wb + ks * 512);
        }
    }
    short8 af[KSTEPS];
    {
        int m = lane & 15;
        int kb = (lane >> 4) << 3;
        unsigned base = (unsigned)(m * (SIN * 2));
        unsigned swz = (unsigned)((m & 7) << 4);
#pragma unroll
        for (int ks = 0; ks < KSTEPS; ++ks) {
            unsigned addr = (base + (unsigned)((ks * 32 + kb) * 2)) ^ swz;
            af[ks] = *(const short8*)((const char*)Ain + addr);
        }
    }
    f32x4 acc[MAXNT];
#pragma unroll
    for (int i = 0; i < MAXNT; ++i) {
        acc[i] = (f32x4){0.f, 0.f, 0.f, 0.f};
        if (i < myNT) {
#pragma unroll
            for (int ks = 0; ks < KSTEPS; ++ks)
                acc[i] = __builtin_amdgcn_mfma_f32_16x16x32_bf16(af[ks], wf[i][ks], acc[i], 0, 0, 0);
        }
    }
#pragma unroll
    for (int i = 0; i < MAXNT; ++i) {
        if (i < myNT) {
            int nt = wv + i * 4;
            int n = nt * 16 + (lane & 15);
            float bb = bias[n];
#pragma unroll
            for (int r = 0; r < 4; ++r) {
                int m = ((lane >> 4) << 2) + r;
                float v = celu01(acc[i][r] + bb);
                if (OUTF32) {
                    Fout[m * NOUT + n] = v;
                } else {
                    unsigned addr = (unsigned)(m * (NOUT * 2) + n * 2) ^ ((unsigned)((m & 7) << 4));
                    *(ushort_t*)((char*)Aout + addr) = f2bf(v);
                }
            }
        }
    }
    __syncthreads();
}

// ---------------------------------------------------------------------------
// MEGA kernel (cooperative): phase1 sort+repack | gsync | phase2 AEV (8
// tasks/wave) | gsync | phase3 MLP + deterministic completion reduce.
// 448 blocks x 256 threads; LDS union <= 40064 B; VGPR capped by
// __launch_bounds__(256,2) -> 2 waves/SIMD -> 512-block co-residency cap.
// ---------------------------------------------------------------------------
__global__ __launch_bounds__(256, 2) void mega_kernel(
    const int* __restrict__ species, const float* __restrict__ coords,
    const float* __restrict__ W0, const float* __restrict__ W1,
    const float* __restrict__ W2,
    const float* __restrict__ b0, const float* __restrict__ b1,
    const float* __restrict__ b2,
    const float* __restrict__ W3, const float* __restrict__ b3,
    int* __restrict__ seg, float4* __restrict__ cxyz,
    unsigned* __restrict__ counter, float* __restrict__ cvec,
    ushort_t* __restrict__ aevb,
    ushort_t* __restrict__ wr0, ushort_t* __restrict__ wr1,
    ushort_t* __restrict__ wr2,
    float* __restrict__ ebuf, float* __restrict__ out)
{
    __shared__ __align__(16) char smem[40064];
    int t = threadIdx.x;
    int lane = t & 63, wv = t >> 6;
    int bid = blockIdx.x;
    cg::grid_group grid = cg::this_grid();

    // ================= phase 1: sort (block 0) + repack (blocks 1..385) ====
    if (bid == 0) {
        int (*cnt)[NSP] = (int(*)[NSP])smem;                 // 7168 B
        int (*wsum)[NSP] = (int(*)[NSP])(smem + 7168);       // 112 B
        int* sortedL = (int*)(smem + 7280);                  // 8192 B
        float* cloc = (float*)(smem + 15472);                // 24576 B

        if (t == 0) counter[0] = 0u;
        // coalesced coords -> LDS (latency hides under the scans)
#pragma unroll
        for (int i = 0; i < 24; ++i) cloc[t + i * 256] = coords[t + i * 256];

        // ladder constants for phase 2
        if (t < 14) {
            float v;
            if (t < 6) {
                int i = t >> 1, hi = t & 1;
                float b = c_mue[i + (hi ? 4 : 0)];
                float a = c_mue[i + (hi ? 5 : 1)];
                v = nexp2(CS_LOG2E * (a * a - b * b));
            } else {
                int j = t - 6;
                float me = c_mue[j], mo = me + 0.26f;
                v = nexp2(CS_LOG2E * (mo * mo - me * me));
            }
            cvec[t] = v;
        }

        // counting sort: 256 threads, 8 atoms/thread
        int c[NSP], incl[NSP], spl[8];
#pragma unroll
        for (int s = 0; s < NSP; ++s) c[s] = 0;
#pragma unroll
        for (int i = 0; i < 8; ++i) {
            int s = species[t * 8 + i];
            spl[i] = s;
#pragma unroll
            for (int q = 0; q < NSP; ++q) c[q] += (s == q) ? 1 : 0;
        }
#pragma unroll
        for (int s = 0; s < NSP; ++s) {
            int v = c[s];
            for (int d = 1; d < 64; d <<= 1) {
                int o = __shfl_up(v, d);
                if (lane >= d) v += o;
            }
            incl[s] = v;
            if (lane == 63) wsum[wv][s] = v;
        }
        __syncthreads();

        int bs[NSP];
        int run = 0;
#pragma unroll
        for (int s = 0; s < NSP; ++s) {
            int w0 = wsum[0][s], w1 = wsum[1][s], w2 = wsum[2][s], w3 = wsum[3][s];
            int woff = (wv > 0 ? w0 : 0) + (wv > 1 ? w1 : 0) + (wv > 2 ? w2 : 0);
            int tot = w0 + w1 + w2 + w3;
            bs[s] = run + woff + incl[s] - c[s];
            if (t == 0) seg[s] = run;
            run += tot;
        }
        if (t == 0) seg[NSP] = run;

#pragma unroll
        for (int s = 0; s < NSP; ++s) cnt[t][s] = bs[s];
#pragma unroll
        for (int i = 0; i < 8; ++i) {
            int s = spl[i];
            int pos = cnt[t][s]++;
            sortedL[pos] = t * 8 + i;
        }
        __syncthreads();

        for (int p = t; p < N_ATOMS; p += 256) {
            int j = sortedL[p];
            cxyz[p] = make_float4(cloc[3 * j + 0], cloc[3 * j + 1],
                                  cloc[3 * j + 2], 0.f);
        }
    } else {
        int g = (bid - 1) * 256 + t;
        if (g < PREP_GT) repack_unit(g, W0, W1, W2, wr0, wr1, wr2);
    }

    grid.sync();

    // ================= phase 2: AEV, 8 tasks per wave =====================
    {
        f32x2 cke0 = (f32x2){cvec[0], cvec[1]};
        f32x2 cke1 = (f32x2){cvec[2], cvec[3]};
        f32x2 cke2 = (f32x2){cvec[4], cvec[5]};
        float cko[8];
#pragma unroll
        for (int j = 0; j < 8; ++j) cko[j] = cvec[6 + j];

        int wave_id = bid * 4 + wv;          // 0..1791
        int gbase = wave_id * 8;
        for (int i = 0; i < 8; ++i)
            aev_task(gbase + i, lane, seg, cxyz, aevb, cke0, cke1, cke2, cko);
    }

    grid.sync();

    // ================= phase 3: MLP (blocks 0..134) =======================
    if (bid < NBLK_MLP) {
        ushort_t* bufA = (ushort_t*)smem;              // 8192
        ushort_t* bufB = (ushort_t*)(smem + 8192);     // 8192
        float* h2f = (float*)(smem + 16384);           // 10240
        float* ered = (float*)(smem + 26624);          // 64
        float* wred = (float*)(smem + 26688);          // 16
        int* islast = (int*)(smem + 26704);

        int sfound = -1, tile = 0, segbase = 0, na = 0;
        int t0 = 0;
        for (int s = 0; s < NSP; ++s) {
            int beg = seg[s], end = seg[s + 1];
            int n = end - beg;
            int nt = (n + MTILE - 1) >> 4;
            if (sfound < 0 && bid < t0 + nt) {
                sfound = s; tile = bid - t0; segbase = beg;
                int rem = n - tile * MTILE;
                na = rem < MTILE ? rem : MTILE;
            }
            t0 += nt;
        }

        float ssum = 0.f;
        if (sfound >= 0) {
            int s = sfound;
            int row0 = segbase + tile * MTILE;

            float w3v[10];
            {
                const float* w3 = W3 + (size_t)s * 160 + (t & 15);
#pragma unroll
                for (int j = 0; j < 10; ++j) w3v[j] = w3[j * 16];
            }

            // stage AEV rows (bf16, swizzled); rows>=na, cols>=112 zeroed
            {
                int m = t >> 4, piece = t & 15;
                short8 v = (short8){0,0,0,0,0,0,0,0};
                if (m < na && piece < 14)
                    v = *(const short8*)(aevb + (size_t)(row0 + m) * AEVD + piece * 8);
                unsigned addr = (unsigned)(m * 256 + piece * 16) ^ ((unsigned)((m & 7) << 4));
                *(short8*)((char*)bufA + addr) = v;
            }
            __syncthreads();

            compute_layer4<4, 16, 128, 256, false>(wr0 + (size_t)s * 16 * 4 * 512,
                                                   b0 + s * 256, bufA, bufB, nullptr, lane, wv);
            compute_layer4<8, 12, 256, 192, false>(wr1 + (size_t)s * 12 * 8 * 512,
                                                   b1 + s * 192, bufB, bufA, nullptr, lane, wv);
            compute_layer4<6, 10, 192, 160, true >(wr2 + (size_t)s * 10 * 6 * 512,
                                                   b2 + s * 160, bufA, nullptr, h2f, lane, wv);

            // Layer 3: 160 -> 1 per atom (16 lanes per atom, 16 atoms)
            {
                int a = t >> 4, l = t & 15;
                float part = 0.f;
#pragma unroll
                for (int j = 0; j < 10; ++j)
                    part = fmaf(h2f[a * 160 + l + j * 16], w3v[j], part);
#pragma unroll
                for (int off = 8; off; off >>= 1) part += __shfl_down(part, off, 16);
                if (l == 0) ered[a] = part;
            }
            __syncthreads();
            if (t < 16) {
                float v = (t < na) ? ered[t] : 0.f;
#pragma unroll
                for (int off = 8; off; off >>= 1) v += __shfl_down(v, off, 16);
                if (t == 0) ssum = v + (float)na * b3[s];
            }
        }

        if (t == 0) {
            ebuf[bid] = ssum;
            __threadfence();
            unsigned old = atomicAdd(counter, 1u);
            *islast = (old == (unsigned)(NBLK_MLP - 1)) ? 1 : 0;
        }
        __syncthreads();
        if (*islast) {
            __threadfence();
            float v = (t < NBLK_MLP) ? ebuf[t] : 0.f;
#pragma unroll
            for (int off = 32; off; off >>= 1) v += __shfl_down(v, off);
            if (lane == 0) wred[wv] = v;
            __syncthreads();
            if (t == 0) {
                float tot = 0.f;
#pragma unroll
                for (int i = 0; i < 4; ++i) tot += wred[i];
                out[0] = tot;
            }
        }
    }
}

// ===========================================================================
// FALLBACK path: the proven R7 three-kernel pipeline (unchanged).
// ===========================================================================
__global__ __launch_bounds__(1024) void sortprep_kernel(
    const int* __restrict__ species, const float* __restrict__ coords,
    int* __restrict__ seg, float4* __restrict__ cxyz,
    unsigned* __restrict__ counter, float* __restrict__ cvec,
    const float* __restrict__ W0, const float* __restrict__ W1,
    const float* __restrict__ W2,
    ushort_t* __restrict__ wr0, ushort_t* __restrict__ wr1,
    ushort_t* __restrict__ wr2)
{
    __shared__ int wsum[16][NSP];
    __shared__ int wpre[16][NSP];
    __shared__ int sortedL[N_ATOMS];
    __shared__ float cloc[3 * N_ATOMS];
    int t = threadIdx.x;

    if (blockIdx.x != 0) {
        int g = (blockIdx.x - 1) * 1024 + t;
        if (g < PREP_GT) repack_unit(g, W0, W1, W2, wr0, wr1, wr2);
        return;
    }

#pragma unroll
    for (int i = 0; i < 6; ++i) cloc[t + i * 1024] = coords[t + i * 1024];

    if (t < 14) {
        float v;
        if (t < 6) {
            int i = t >> 1, hi = t & 1;
            float b = c_mue[i + (hi ? 4 : 0)];
            float a = c_mue[i + (hi ? 5 : 1)];
            v = nexp2(CS_LOG2E * (a * a - b * b));
        } else {
            int j = t - 6;
            float me = c_mue[j], mo = me + 0.26f;
            v = nexp2(CS_LOG2E * (mo * mo - me * me));
        }
        cvec[t] = v;
    }

    int lane = t & 63, wv = t >> 6;
    if (t == 0) counter[0] = 0u;

    int s0 = species[2 * t], s1 = species[2 * t + 1];
    int c[NSP], incl[NSP];
#pragma unroll
    for (int s = 0; s < NSP; ++s) c[s] = (s0 == s ? 1 : 0) + (s1 == s ? 1 : 0);
#pragma unroll
    for (int s = 0; s < NSP; ++s) {
        int v = c[s];
        for (int d = 1; d < 64; d <<= 1) {
            int o = __shfl_up(v, d);
            if (lane >= d) v += o;
        }
        incl[s] = v;
        if (lane == 63) wsum[wv][s] = v;
    }
    __syncthreads();

    if (t < 112) {
        int s = t >> 4;
        int w = t & 15;
        int v = wsum[w][s];
        for (int d = 1; d < 16; d <<= 1) {
            int o = __shfl_up(v, d, 16);
            if ((t & 15) >= d) v += o;
        }
        wpre[w][s] = v;
    }
    __syncthreads();

    int bs[NSP];
    int run = 0;
#pragma unroll
    for (int s = 0; s < NSP; ++s) {
        int tot = wpre[15][s];
        int woff = wpre[wv][s] - wsum[wv][s];
        bs[s] = run + woff + incl[s] - c[s];
        if (t == 0) seg[s] = run;
        run += tot;
    }
    if (t == 0) seg[NSP] = run;

    {
        int p0 = bs[s0]++; sortedL[p0] = 2 * t;
        int p1 = bs[s1]++; sortedL[p1] = 2 * t + 1;
    }
    __syncthreads();

    for (int p = t; p < N_ATOMS; p += 1024) {
        int j = sortedL[p];
        cxyz[p] = make_float4(cloc[3 * j + 0], cloc[3 * j + 1],
                              cloc[3 * j + 2], 0.f);
    }
}

__global__ __launch_bounds__(256) void aev_kernel(
    const int* __restrict__ seg, const float4* __restrict__ cxyz,
    const float* __restrict__ cvec, ushort_t* __restrict__ aevb)
{
    int t = threadIdx.x;
    int jl = t & 63;
    int gid = blockIdx.x * 4 + (t >> 6);
    f32x2 cke0 = (f32x2){cvec[0], cvec[1]};
    f32x2 cke1 = (f32x2){cvec[2], cvec[3]};
    f32x2 cke2 = (f32x2){cvec[4], cvec[5]};
    float cko[8];
#pragma unroll
    for (int j = 0; j < 8; ++j) cko[j] = cvec[6 + j];
    aev_task(gid, jl, seg, cxyz, aevb, cke0, cke1, cke2, cko);
}

template<int KSTEPS, int NT>
__device__ __forceinline__ void load_wf(const ushort_t* __restrict__ wrep,
                                        short8 (&wf)[(NT + 7) / 8][KSTEPS],
                                        int lane, int wv)
{
    constexpr int MAXNT = (NT + 7) / 8;
    const int myNT = (NT - wv + 7) / 8;
#pragma unroll
    for (int i = 0; i < MAXNT; ++i) {
        if (i < myNT) {
            int nt = wv + i * 8;
            const ushort_t* wb = wrep + ((size_t)nt * KSTEPS) * 512 + lane * 8;
#pragma unroll
            for (int ks = 0; ks < KSTEPS; ++ks)
                wf[i][ks] = *(const short8*)(wb + ks * 512);
        }
    }
}

template<int KSTEPS, int NT, int SIN, int NOUT, bool OUTF32, int NKSTEPS, int NNT, bool PREF>
__device__ __forceinline__ void compute_layer8(
    const float* __restrict__ bias,
    const ushort_t* Ain, ushort_t* Aout, float* Fout,
    short8 (&wf)[(NT + 7) / 8][KSTEPS],
    const ushort_t* __restrict__ nwrep,
    short8 (&nwf)[(NNT + 7) / 8][NKSTEPS],
    int lane, int wv)
{
    constexpr int MAXNT = (NT + 7) / 8;
    const int myNT = (NT - wv + 7) / 8;

    if constexpr (PREF) {
        load_wf<NKSTEPS, NNT>(nwrep, nwf, lane, wv);
    }

    short8 af[KSTEPS];
    {
        int m = lane & 15;
        int kb = (lane >> 4) << 3;
        unsigned base = (unsigned)(m * (SIN * 2));
        unsigned swz = (unsigned)((m & 7) << 4);
#pragma unroll
        for (int ks = 0; ks < KSTEPS; ++ks) {
            unsigned addr = (base + (unsigned)((ks * 32 + kb) * 2)) ^ swz;
            af[ks] = *(const short8*)((const char*)Ain + addr);
        }
    }
    f32x4 acc[MAXNT];
#pragma unroll
    for (int i = 0; i < MAXNT; ++i) {
        acc[i] = (f32x4){0.f, 0.f, 0.f, 0.f};
        if (i < myNT) {
#pragma unroll
            for (int ks = 0; ks < KSTEPS; ++ks)
                acc[i] = __builtin_amdgcn_mfma_f32_16x16x32_bf16(af[ks], wf[i][ks], acc[i], 0, 0, 0);
        }
    }
#pragma unroll
    for (int i = 0; i < MAXNT; ++i) {
        if (i < myNT) {
            int nt = wv + i * 8;
            int n = nt * 16 + (lane & 15);
            float bb = bias[n];
#pragma unroll
            for (int r = 0; r < 4; ++r) {
                int m = ((lane >> 4) << 2) + r;
                float v = celu01(acc[i][r] + bb);
                if (OUTF32) {
                    Fout[m * NOUT + n] = v;
                } else {
                    unsigned addr = (unsigned)(m * (NOUT * 2) + n * 2) ^ ((unsigned)((m & 7) << 4));
                    *(ushort_t*)((char*)Aout + addr) = f2bf(v);
                }
            }
        }
    }
    __syncthreads();
}

__global__ __launch_bounds__(512, 1) void mlp_kernel(
    const int* __restrict__ seg, const ushort_t* __restrict__ aevb,
    const ushort_t* __restrict__ wr0, const ushort_t* __restrict__ wr1,
    const ushort_t* __restrict__ wr2,
    const float* __restrict__ b0, const float* __restrict__ b1,
    const float* __restrict__ b2,
    const float* __restrict__ W3, const float* __restrict__ b3,
    float* __restrict__ ebuf, unsigned* __restrict__ counter,
    float* __restrict__ out)
{
    __shared__ __align__(16) ushort_t bufA[16 * 256];
    __shared__ __align__(16) ushort_t bufB[16 * 256];
    __shared__ __align__(16) float h2f[16 * 160];
    __shared__ float ered[MTILE];
    __shared__ float wred[8];
    __shared__ int islast;

    int t = threadIdx.x;
    int lane = t & 63, wv = t >> 6;
    int bid = blockIdx.x;

    int sfound = -1, tile = 0, segbase = 0, na = 0;
    int t0 = 0;
    for (int s = 0; s < NSP; ++s) {
        int beg = seg[s], end = seg[s + 1];
        int n = end - beg;
        int nt = (n + MTILE - 1) >> 4;
        if (sfound < 0 && bid < t0 + nt) {
            sfound = s; tile = bid - t0; segbase = beg;
            int rem = n - tile * MTILE;
            na = rem < MTILE ? rem : MTILE;
        }
        t0 += nt;
    }

    float ssum = 0.f;
    if (sfound >= 0) {
        int s = sfound;
        int row0 = segbase + tile * MTILE;

        float w3v[5];
        {
            const float* w3 = W3 + (size_t)s * 160 + (t & 31);
#pragma unroll
            for (int j = 0; j < 5; ++j) w3v[j] = w3[j * 32];
        }

        short8 wf0[2][4];
        short8 wf1[2][8];
        short8 wf2[2][6];
        short8 wfd[1][1];
        load_wf<4, 16>(wr0 + (size_t)s * 16 * 4 * 512, wf0, lane, wv);

        if (t < 256) {
            int m = t >> 4, piece = t & 15;
            short8 v = (short8){0,0,0,0,0,0,0,0};
            if (m < na && piece < 14)
                v = *(const short8*)(aevb + (size_t)(row0 + m) * AEVD + piece * 8);
            unsigned addr = (unsigned)(m * 256 + piece * 16) ^ ((unsigned)((m & 7) << 4));
            *(short8*)((char*)bufA + addr) = v;
        }
        __syncthreads();

        compute_layer8<4, 16, 128, 256, false, 8, 12, true>(
            b0 + s * 256, bufA, bufB, nullptr, wf0,
            wr1 + (size_t)s * 12 * 8 * 512, wf1, lane, wv);
        compute_layer8<8, 12, 256, 192, false, 6, 10, true>(
            b1 + s * 192, bufB, bufA, nullptr, wf1,
            wr2 + (size_t)s * 10 * 6 * 512, wf2, lane, wv);
        compute_layer8<6, 10, 192, 160, true, 1, 1, false>(
            b2 + s * 160, bufA, nullptr, h2f, wf2,
            nullptr, wfd, lane, wv);

        {
            int a = t >> 5, l = t & 31;
            float part = 0.f;
#pragma unroll
            for (int j = 0; j < 5; ++j) part = fmaf(h2f[a * 160 + l + j * 32], w3v[j], part);
            for (int off = 16; off; off >>= 1) part += __shfl_down(part, off, 32);
            if (l == 0) ered[a] = part;
        }
        __syncthreads();
        if (t < 16) {
            float v = (t < na) ? ered[t] : 0.f;
#pragma unroll
            for (int off = 8; off; off >>= 1) v += __shfl_down(v, off, 16);
            if (t == 0) ssum = v + (float)na * b3[s];
        }
    }

    if (t == 0) {
        ebuf[bid] = ssum;
        __threadfence();
        unsigned old = atomicAdd(counter, 1u);
        islast = (old == (unsigned)gridDim.x - 1u) ? 1 : 0;
    }
    __syncthreads();
    if (islast) {
        __threadfence();
        float v = (t < NBLK_MLP) ? ebuf[t] : 0.f;
#pragma unroll
        for (int off = 32; off; off >>= 1) v += __shfl_down(v, off);
        if (lane == 0) wred[wv] = v;
        __syncthreads();
        if (t == 0) {
            float tot = 0.f;
#pragma unroll
            for (int i = 0; i < 8; ++i) tot += wred[i];
            out[0] = tot;
        }
    }
}

extern "C" void kernel_launch(void* const* d_in, const int* in_sizes, int n_in,
                              void* d_out, int out_size, void* d_ws, size_t ws_size,
                              hipStream_t stream)
{
    const int*   species = (const int*)d_in[0];
    const float* coords  = (const float*)d_in[1];
    const float* W0 = (const float*)d_in[2];
    const float* b0 = (const float*)d_in[3];
    const float* W1 = (const float*)d_in[4];
    const float* b1 = (const float*)d_in[5];
    const float* W2 = (const float*)d_in[6];
    const float* b2 = (const float*)d_in[7];
    const float* W3 = (const float*)d_in[8];
    const float* b3 = (const float*)d_in[9];
    float* out = (float*)d_out;

    char* ws = (char*)d_ws;
    int*      seg     = (int*)(ws);                   // [0, 32)
    unsigned* counter = (unsigned*)(ws + 48);         // [48, 52)
    float*    ebuf    = (float*)(ws + 64);            // 135 f32 -> ends 604
    float*    cvec    = (float*)(ws + 640);           // 14 f32 ladder constants
    float4*   cxyz    = (float4*)(ws + 1152);         // 2048 float4 (32 KB)
    ushort_t* aevb    = (ushort_t*)(ws + 33920);      // 2048*112 bf16 (448 KB)
    ushort_t* wr0     = (ushort_t*)(ws + 492672);     // 229376 bf16
    ushort_t* wr1     = (ushort_t*)(ws + 951424);     // 344064 bf16
    ushort_t* wr2     = (ushort_t*)(ws + 1639552);    // 215040 bf16

    void* kargs[] = {
        (void*)&species, (void*)&coords,
        (void*)&W0, (void*)&W1, (void*)&W2,
        (void*)&b0, (void*)&b1, (void*)&b2,
        (void*)&W3, (void*)&b3,
        (void*)&seg, (void*)&cxyz, (void*)&counter, (void*)&cvec,
        (void*)&aevb, (void*)&wr0, (void*)&wr1, (void*)&wr2,
        (void*)&ebuf, (void*)&out
    };
    hipError_t rc = hipLaunchCooperativeKernel(mega_kernel, dim3(MEGA_GRID),
                                               dim3(256), kargs, 0, stream);
    if (rc != hipSuccess) {
        (void)hipGetLastError();   // clear sticky error; fall back to R7 path
        hipLaunchKernelGGL(sortprep_kernel, dim3(98), dim3(1024), 0, stream,
                           species, coords, seg, cxyz, counter, cvec,
                           W0, W1, W2, wr0, wr1, wr2);
        hipLaunchKernelGGL(aev_kernel, dim3(AEV_BLKS), dim3(256), 0, stream,
                           seg, cxyz, cvec, aevb);
        hipLaunchKernelGGL(mlp_kernel, dim3(NBLK_MLP), dim3(512), 0, stream,
                           seg, aevb, wr0, wr1, wr2, b0, b1, b2, W3, b3,
                           ebuf, counter, out);
    }
}

// Round 9
// 34.013 us; speedup vs baseline: 4.1331x; 4.1331x over previous
//
#include <hip/hip_runtime.h>
#include <hip/hip_fp16.h>
#include <math.h>

#define N_ATOMS 2048
#define NSP 7
#define AEVD 112      // real radial features; padded to 128 (K-tile) only in LDS
#define MTILE 16      // atoms per MLP block (full 16-row M-tile)
#define NBLK_MLP 135  // max tiles: 2048/16 + 7 slack
#define AEV_TASKS (N_ATOMS * NSP)           // (atom, species) wave-tasks, 16 shells each
#define AEV_BLKS (AEV_TASKS / 4)            // 3584 blocks of 4 waves

typedef __attribute__((ext_vector_type(8))) short short8;
typedef __attribute__((ext_vector_type(4))) float f32x4;
typedef __attribute__((ext_vector_type(2))) float f32x2;
typedef unsigned short ushort_t;

// ---- guaranteed-native transcendentals (single HW instruction) ----
#if !__has_builtin(__builtin_amdgcn_exp2f)
extern "C" __device__ float __ocml_native_exp2_f32(float);
#endif
#if !__has_builtin(__builtin_amdgcn_cosf)
extern "C" __device__ float __ocml_native_cos_f32(float);
#endif
#if !__has_builtin(__builtin_amdgcn_sqrtf)
extern "C" __device__ float __ocml_native_sqrt_f32(float);
#endif

__device__ __forceinline__ float nexp2(float x) {       // 2^x  (v_exp_f32)
#if __has_builtin(__builtin_amdgcn_exp2f)
    return __builtin_amdgcn_exp2f(x);
#else
    return __ocml_native_exp2_f32(x);
#endif
}
__device__ __forceinline__ float ncos_rev(float x) {    // cos(2*pi*x) (v_cos_f32)
#if __has_builtin(__builtin_amdgcn_cosf)
    return __builtin_amdgcn_cosf(x);
#else
    return __ocml_native_cos_f32(x * 6.2831853071795865f);
#endif
}
__device__ __forceinline__ float nsqrt(float x) {       // sqrt(x) (v_sqrt_f32)
#if __has_builtin(__builtin_amdgcn_sqrtf)
    return __builtin_amdgcn_sqrtf(x);
#else
    return __ocml_native_sqrt_f32(x);
#endif
}

// even-shell mus (ladder order; SHFR[2j] = mu_e[j])
__device__ __constant__ float c_mue[8] = {0.9f, 1.43f, 1.96f, 2.49f,
                                          3.02f, 3.55f, 4.08f, 4.61f};

#define CS_LOG2E  (-23.083120654223414f)   // -16*log2(e)
#define CB_LOG2E  ( 46.166241308446828f)   // +32*log2(e)
#define EA_COEF   ( 12.003222740196175f)   // CB_LOG2E * 0.26 (even->odd shell step)
#define EB_COEF   ( 24.468107893476819f)   // CB_LOG2E * 0.53 (even->even shell step)

__device__ __forceinline__ float celu01(float x) {
    return x > 0.f ? x : 0.1f * (nexp2(x * 14.426950f) - 1.f);
}

__device__ __forceinline__ ushort_t f2bf(float v) {   // RNE fp32->bf16
    unsigned u = __float_as_uint(v);
    u += 0x7fffu + ((u >> 16) & 1u);
    return (ushort_t)(u >> 16);
}

__device__ __forceinline__ unsigned pkadd16(unsigned a, unsigned b) {  // v_pk_add_f16
    __half2 x, y;
    __builtin_memcpy(&x, &a, 4);
    __builtin_memcpy(&y, &b, 4);
    __half2 r = __hadd2(x, y);
    unsigned u;
    __builtin_memcpy(&u, &r, 4);
    return u;
}

#define PREP_G0 28672   // 7*16*4*64
#define PREP_G1 43008   // 7*12*8*64
#define PREP_G2 26880   // 7*10*6*64
#define PREP_GT (PREP_G0 + PREP_G1 + PREP_G2)   // 98560 = 385*256

// repack one fragment unit (store offset uses branch-LOCAL g — R2 lesson)
__device__ __forceinline__ void repack_unit(
    int g, const float* __restrict__ W0, const float* __restrict__ W1,
    const float* __restrict__ W2,
    ushort_t* __restrict__ wr0, ushort_t* __restrict__ wr1,
    ushort_t* __restrict__ wr2)
{
    const float* W; ushort_t* dst; int NT, KS, KREAL, KIN, NOUT;
    if (g < PREP_G0)                 { W = W0; dst = wr0; NT = 16; KS = 4; KREAL = 112; KIN = 1008; NOUT = 256; }
    else if (g < PREP_G0 + PREP_G1)  { g -= PREP_G0; W = W1; dst = wr1; NT = 12; KS = 8; KREAL = 256; KIN = 256; NOUT = 192; }
    else                             { g -= PREP_G0 + PREP_G1; W = W2; dst = wr2; NT = 10; KS = 6; KREAL = 192; KIN = 192; NOUT = 160; }
    int L = g & 63, rest = g >> 6;
    int ks = rest % KS; rest /= KS;
    int nt = rest % NT; int s = rest / NT;
    int n = nt * 16 + (L & 15);
    int k0 = ks * 32 + ((L >> 4) << 3);
    const float* src = W + (size_t)s * KIN * NOUT + n;
    short8 v8;
#pragma unroll
    for (int j = 0; j < 8; ++j) {
        int k = k0 + j;
        float v = (k < KREAL) ? src[(size_t)k * NOUT] : 0.f;
        v8[j] = (short)f2bf(v);
    }
    *(short8*)(dst + (size_t)g * 8) = v8;   // LOCAL g (fragment-linear)
}

// ---------------------------------------------------------------------------
// Kernel 1: PURE sort (1 block, 1024 threads, 2 atoms/thread, two-stage
// scan) + ladder-constant precompute.  R9: repack moved to the AEV kernel
// (it depends only on W, not on the sort) — kernel 1 critical path is now
// sort-only, so the AEV launch gates only on the sort.
// ---------------------------------------------------------------------------
__global__ __launch_bounds__(1024) void sort_kernel(
    const int* __restrict__ species, const float* __restrict__ coords,
    int* __restrict__ seg, float4* __restrict__ cxyz,
    unsigned* __restrict__ counter, float* __restrict__ cvec)
{
    __shared__ int wsum[16][NSP];   // per-wave per-species counts
    __shared__ int wpre[16][NSP];   // inclusive prefix over waves
    __shared__ int sortedL[N_ATOMS];
    __shared__ float cloc[3 * N_ATOMS];   // 24 KB staged coords
    int t = threadIdx.x;

    // coalesced coords -> LDS (latency hides under the scans)
#pragma unroll
    for (int i = 0; i < 6; ++i) cloc[t + i * 1024] = coords[t + i * 1024];

    // ladder constants: cvec[0..5] = cke pairs {lo,hi} x3; cvec[6..13] = cko
    if (t < 14) {
        float v;
        if (t < 6) {
            int i = t >> 1, hi = t & 1;
            float b = c_mue[i + (hi ? 4 : 0)];
            float a = c_mue[i + (hi ? 5 : 1)];
            v = nexp2(CS_LOG2E * (a * a - b * b));
        } else {
            int j = t - 6;
            float me = c_mue[j], mo = me + 0.26f;
            v = nexp2(CS_LOG2E * (mo * mo - me * me));
        }
        cvec[t] = v;
    }

    int lane = t & 63, wv = t >> 6;
    if (t == 0) counter[0] = 0u;

    int s0 = species[2 * t], s1 = species[2 * t + 1];
    int c[NSP], incl[NSP];
#pragma unroll
    for (int s = 0; s < NSP; ++s) c[s] = (s0 == s ? 1 : 0) + (s1 == s ? 1 : 0);
#pragma unroll
    for (int s = 0; s < NSP; ++s) {
        int v = c[s];
        for (int d = 1; d < 64; d <<= 1) {
            int o = __shfl_up(v, d);
            if (lane >= d) v += o;
        }
        incl[s] = v;
        if (lane == 63) wsum[wv][s] = v;
    }
    __syncthreads();

    // cross-wave scan: 112 lanes (2 waves), width-16 shfl scan per species
    if (t < 112) {
        int s = t >> 4;
        int w = t & 15;
        int v = wsum[w][s];
        for (int d = 1; d < 16; d <<= 1) {
            int o = __shfl_up(v, d, 16);
            if ((t & 15) >= d) v += o;
        }
        wpre[w][s] = v;                     // inclusive over waves 0..w
    }
    __syncthreads();

    int bs[NSP];
    int run = 0;
#pragma unroll
    for (int s = 0; s < NSP; ++s) {
        int tot = wpre[15][s];
        int woff = wpre[wv][s] - wsum[wv][s];          // exclusive wave prefix
        bs[s] = run + woff + incl[s] - c[s];           // exclusive lane prefix
        if (t == 0) seg[s] = run;
        run += tot;
    }
    if (t == 0) seg[NSP] = run;

    // stable scatter of this thread's 2 atoms
    {
        int p0 = bs[s0]++; sortedL[p0] = 2 * t;
        int p1 = bs[s1]++; sortedL[p1] = 2 * t + 1;
    }
    __syncthreads();

    for (int p = t; p < N_ATOMS; p += 1024) {
        int j = sortedL[p];
        cxyz[p] = make_float4(cloc[3 * j + 0], cloc[3 * j + 1],
                              cloc[3 * j + 2], 0.f);
    }
}

// ---------------------------------------------------------------------------
// Kernel 2: radial AEV (one wave-task = (atom,species), 16 shells) +
// R9: blocks 0..384 also repack one 256-unit weight slice (independent of
// the sort; ~1 µs of work absorbed into a 3584-block grid).
// Packed-f32 two-anchor ladder; cvec constants; fold-reduction (34 ops).
// ---------------------------------------------------------------------------
__global__ __launch_bounds__(256) void aev_kernel(
    const int* __restrict__ seg, const float4* __restrict__ cxyz,
    const float* __restrict__ cvec, ushort_t* __restrict__ aevb,
    const float* __restrict__ W0, const float* __restrict__ W1,
    const float* __restrict__ W2,
    ushort_t* __restrict__ wr0, ushort_t* __restrict__ wr1,
    ushort_t* __restrict__ wr2)
{
    int t = threadIdx.x;
    int jl = t & 63;

    // weight repack slice (blocks 0..384; depends only on W inputs)
    if (blockIdx.x < 385) {
        int g = blockIdx.x * 256 + t;
        if (g < PREP_GT) repack_unit(g, W0, W1, W2, wr0, wr1, wr2);
    }

    int gid = blockIdx.x * 4 + (t >> 6);   // 0 .. 14335
    int atom = gid / 7;                    // magic-mul const div
    int s = gid - atom * 7;

    const float BE_A0 = CB_LOG2E * 0.9f;
    const float GE_A0 = CS_LOG2E * (0.9f * 0.9f);
    const float BE_A1 = CB_LOG2E * 3.02f;
    const float GE_A1 = CS_LOG2E * (3.02f * 3.02f);

    float4 ci = cxyz[atom];
    float xi = ci.x, yi = ci.y, zi = ci.z;
    int pb = seg[s], pe = seg[s + 1];

    // ladder constants (uniform -> scalar loads)
    f32x2 cke0 = (f32x2){cvec[0], cvec[1]};
    f32x2 cke1 = (f32x2){cvec[2], cvec[3]};
    f32x2 cke2 = (f32x2){cvec[4], cvec[5]};
    float cko[8];
#pragma unroll
    for (int j = 0; j < 8; ++j) cko[j] = cvec[6 + j];

    f32x2 accE[4], accO[4];
#pragma unroll
    for (int i = 0; i < 4; ++i) {
        accE[i] = (f32x2){0.f, 0.f};
        accO[i] = (f32x2){0.f, 0.f};
    }

    const float4* pj = cxyz + pb + jl;
    for (int n = pe - pb - jl; n > 0; n -= 64, pj += 64) {
        float4 cj = *pj;                           // L1-resident (32KB total)
        float dx = cj.x - xi, dy = cj.y - yi, dz = cj.z - zi;
        float sq = fmaf(dx, dx, fmaf(dy, dy, dz * dz));
        float d  = nsqrt(sq);
        float dc = fminf(d, 5.2f);                 // clamp: keeps eb/ea finite; fc(5.2)=0
        float fc = fmaf(0.5f, ncos_rev(dc * 0.09615384615f), 0.5f);
        float uc = CS_LOG2E * sq;
        float ea = nexp2(dc * EA_COEF);            // even->odd ratio (shared)
        float fe = ea * fc;
        float ebv = nexp2(dc * EB_COEF);           // even->even ratio (shared)
        f32x2 eb2 = (f32x2){ebv, ebv};
        f32x2 fc2 = (f32x2){fc, fc};
        f32x2 fe2 = (f32x2){fe, fe};
        f32x2 ek0 = eb2 * cke0;
        f32x2 ek1 = eb2 * cke1;
        f32x2 ek2 = eb2 * cke2;
        f32x2 ve = (f32x2){ nexp2(fmaf(dc, BE_A0, uc) + GE_A0),
                            nexp2(fmaf(dc, BE_A1, uc) + GE_A1) };
        accE[0] = ve * fc2 + accE[0];  accO[0] = ve * fe2 + accO[0];
        ve = ve * ek0;
        accE[1] = ve * fc2 + accE[1];  accO[1] = ve * fe2 + accO[1];
        ve = ve * ek1;
        accE[2] = ve * fc2 + accE[2];  accO[2] = ve * fe2 + accO[2];
        ve = ve * ek2;
        accE[3] = ve * fc2 + accE[3];  accO[3] = ve * fe2 + accO[3];
    }

    // subtract the self-pair: exact replica of the in-loop ladder at sq=0
    if (pb <= atom && atom < pe && ((atom - pb) & 63) == jl) {
        f32x2 ve = (f32x2){ nexp2(GE_A0), nexp2(GE_A1) };
        accE[0] -= ve;  accO[0] -= ve;
        ve = ve * cke0;
        accE[1] -= ve;  accO[1] -= ve;
        ve = ve * cke1;
        accE[2] -= ve;  accO[2] -= ve;
        ve = ve * cke2;
        accE[3] -= ve;  accO[3] -= ve;
    }

    // pack to half2 words: hu[j] = {E[j], O[j]*cko[j]} (shells 2j, 2j+1)
    unsigned hu[8];
#pragma unroll
    for (int j = 0; j < 8; ++j) {
        float E = (j < 4) ? accE[j][0] : accE[j - 4][1];
        float O = ((j < 4) ? accO[j][0] : accO[j - 4][1]) * cko[j];
        __half2 hh = __floats2half2_rn(E, O);
        __builtin_memcpy(&hu[j], &hh, 4);
    }

    // ---- fold-reduction: 34 ops vs 96 for the full butterfly ----
    bool hi5 = (jl & 32) != 0;
#pragma unroll
    for (int j = 0; j < 4; ++j) {
        unsigned snd = hi5 ? hu[j] : hu[j + 4];
        unsigned rcv = (unsigned)__shfl_xor((int)snd, 32);
        unsigned kp  = hi5 ? hu[j + 4] : hu[j];
        hu[j] = pkadd16(kp, rcv);
    }
    bool hi4 = (jl & 16) != 0;
#pragma unroll
    for (int j = 0; j < 2; ++j) {
        unsigned snd = hi4 ? hu[j] : hu[j + 2];
        unsigned rcv = (unsigned)__shfl_xor((int)snd, 16);
        unsigned kp  = hi4 ? hu[j + 2] : hu[j];
        hu[j] = pkadd16(kp, rcv);
    }
    bool hi3 = (jl & 8) != 0;
    {
        unsigned snd = hi3 ? hu[0] : hu[1];
        unsigned rcv = (unsigned)__shfl_xor((int)snd, 8);
        unsigned kp  = hi3 ? hu[1] : hu[0];
        hu[0] = pkadd16(kp, rcv);
    }
#pragma unroll
    for (int off = 4; off; off >>= 1)
        hu[0] = pkadd16(hu[0], (unsigned)__shfl_xor((int)hu[0], off));

    // word w = (jl>>3)&7 lives on lanes 8w..8w+7; lane 8w writes shells (2w,2w+1)
    if ((jl & 7) == 0) {
        int w = jl >> 3;
        __half2 hv;
        __builtin_memcpy(&hv, &hu[0], 4);
        float2 f = __half22float2(hv);
        unsigned pk = (unsigned)f2bf(f.x) | ((unsigned)f2bf(f.y) << 16);
        *(unsigned*)(aevb + (size_t)atom * AEVD + s * 16 + 2 * w) = pk;
    }
}

// ---------------------------------------------------------------------------
// Kernel 3: MFMA MLP — 512 threads, 8 waves split the N-tiles.  Next-layer
// weight fragments prefetched BEFORE the current layer's MFMAs; L0 weights
// issued before the staging sync; parallel ered/ebuf reductions (R7).
// ---------------------------------------------------------------------------

template<int KSTEPS, int NT>
__device__ __forceinline__ void load_wf(const ushort_t* __restrict__ wrep,
                                        short8 (&wf)[(NT + 7) / 8][KSTEPS],
                                        int lane, int wv)
{
    constexpr int MAXNT = (NT + 7) / 8;
    const int myNT = (NT - wv + 7) / 8;
#pragma unroll
    for (int i = 0; i < MAXNT; ++i) {
        if (i < myNT) {
            int nt = wv + i * 8;
            const ushort_t* wb = wrep + ((size_t)nt * KSTEPS) * 512 + lane * 8;
#pragma unroll
            for (int ks = 0; ks < KSTEPS; ++ks)
                wf[i][ks] = *(const short8*)(wb + ks * 512);
        }
    }
}

template<int KSTEPS, int NT, int SIN, int NOUT, bool OUTF32, int NKSTEPS, int NNT, bool PREF>
__device__ __forceinline__ void compute_layer8(
    const float* __restrict__ bias,
    const ushort_t* Ain,                 // LDS bf16 [16][SIN], swizzled
    ushort_t* Aout,                      // LDS bf16 [16][NOUT], swizzled
    float* Fout,                         // LDS fp32 [16][NOUT] (if OUTF32)
    short8 (&wf)[(NT + 7) / 8][KSTEPS],  // preloaded B fragments for THIS layer
    const ushort_t* __restrict__ nwrep,  // next-layer weight base
    short8 (&nwf)[(NNT + 7) / 8][NKSTEPS],
    int lane, int wv)
{
    constexpr int MAXNT = (NT + 7) / 8;
    const int myNT = (NT - wv + 7) / 8;

    if constexpr (PREF) {
        load_wf<NKSTEPS, NNT>(nwrep, nwf, lane, wv);
    }

    short8 af[KSTEPS];
    {
        int m = lane & 15;
        int kb = (lane >> 4) << 3;
        unsigned base = (unsigned)(m * (SIN * 2));
        unsigned swz = (unsigned)((m & 7) << 4);
#pragma unroll
        for (int ks = 0; ks < KSTEPS; ++ks) {
            unsigned addr = (base + (unsigned)((ks * 32 + kb) * 2)) ^ swz;
            af[ks] = *(const short8*)((const char*)Ain + addr);
        }
    }
    f32x4 acc[MAXNT];
#pragma unroll
    for (int i = 0; i < MAXNT; ++i) {
        acc[i] = (f32x4){0.f, 0.f, 0.f, 0.f};
        if (i < myNT) {
#pragma unroll
            for (int ks = 0; ks < KSTEPS; ++ks)
                acc[i] = __builtin_amdgcn_mfma_f32_16x16x32_bf16(af[ks], wf[i][ks], acc[i], 0, 0, 0);
        }
    }
#pragma unroll
    for (int i = 0; i < MAXNT; ++i) {
        if (i < myNT) {
            int nt = wv + i * 8;
            int n = nt * 16 + (lane & 15);
            float bb = bias[n];
#pragma unroll
            for (int r = 0; r < 4; ++r) {
                int m = ((lane >> 4) << 2) + r;
                float v = celu01(acc[i][r] + bb);
                if (OUTF32) {
                    Fout[m * NOUT + n] = v;
                } else {
                    unsigned addr = (unsigned)(m * (NOUT * 2) + n * 2) ^ ((unsigned)((m & 7) << 4));
                    *(ushort_t*)((char*)Aout + addr) = f2bf(v);
                }
            }
        }
    }
    __syncthreads();
}

__global__ __launch_bounds__(512, 1) void mlp_kernel(
    const int* __restrict__ seg, const ushort_t* __restrict__ aevb,
    const ushort_t* __restrict__ wr0, const ushort_t* __restrict__ wr1,
    const ushort_t* __restrict__ wr2,
    const float* __restrict__ b0, const float* __restrict__ b1,
    const float* __restrict__ b2,
    const float* __restrict__ W3, const float* __restrict__ b3,
    float* __restrict__ ebuf, unsigned* __restrict__ counter,
    float* __restrict__ out)
{
    __shared__ __align__(16) ushort_t bufA[16 * 256];
    __shared__ __align__(16) ushort_t bufB[16 * 256];
    __shared__ __align__(16) float h2f[16 * 160];
    __shared__ float ered[MTILE];
    __shared__ float wred[8];
    __shared__ int islast;

    int t = threadIdx.x;
    int lane = t & 63, wv = t >> 6;
    int bid = blockIdx.x;

    int sfound = -1, tile = 0, segbase = 0, na = 0;
    int t0 = 0;
    for (int s = 0; s < NSP; ++s) {
        int beg = seg[s], end = seg[s + 1];
        int n = end - beg;
        int nt = (n + MTILE - 1) >> 4;
        if (sfound < 0 && bid < t0 + nt) {
            sfound = s; tile = bid - t0; segbase = beg;
            int rem = n - tile * MTILE;
            na = rem < MTILE ? rem : MTILE;
        }
        t0 += nt;
    }

    float ssum = 0.f;
    if (sfound >= 0) {
        int s = sfound;
        int row0 = segbase + tile * MTILE;

        float w3v[5];
        {
            const float* w3 = W3 + (size_t)s * 160 + (t & 31);
#pragma unroll
            for (int j = 0; j < 5; ++j) w3v[j] = w3[j * 32];
        }

        short8 wf0[2][4];
        short8 wf1[2][8];
        short8 wf2[2][6];
        short8 wfd[1][1];
        load_wf<4, 16>(wr0 + (size_t)s * 16 * 4 * 512, wf0, lane, wv);

        if (t < 256) {
            int m = t >> 4, piece = t & 15;
            short8 v = (short8){0,0,0,0,0,0,0,0};
            if (m < na && piece < 14)
                v = *(const short8*)(aevb + (size_t)(row0 + m) * AEVD + piece * 8);
            unsigned addr = (unsigned)(m * 256 + piece * 16) ^ ((unsigned)((m & 7) << 4));
            *(short8*)((char*)bufA + addr) = v;
        }
        __syncthreads();

        compute_layer8<4, 16, 128, 256, false, 8, 12, true>(
            b0 + s * 256, bufA, bufB, nullptr, wf0,
            wr1 + (size_t)s * 12 * 8 * 512, wf1, lane, wv);
        compute_layer8<8, 12, 256, 192, false, 6, 10, true>(
            b1 + s * 192, bufB, bufA, nullptr, wf1,
            wr2 + (size_t)s * 10 * 6 * 512, wf2, lane, wv);
        compute_layer8<6, 10, 192, 160, true, 1, 1, false>(
            b2 + s * 160, bufA, nullptr, h2f, wf2,
            nullptr, wfd, lane, wv);

        {
            int a = t >> 5, l = t & 31;
            float part = 0.f;
#pragma unroll
            for (int j = 0; j < 5; ++j) part = fmaf(h2f[a * 160 + l + j * 32], w3v[j], part);
            for (int off = 16; off; off >>= 1) part += __shfl_down(part, off, 32);
            if (l == 0) ered[a] = part;
        }
        __syncthreads();
        if (t < 16) {
            float v = (t < na) ? ered[t] : 0.f;
#pragma unroll
            for (int off = 8; off; off >>= 1) v += __shfl_down(v, off, 16);
            if (t == 0) ssum = v + (float)na * b3[s];
        }
    }

    // completion protocol: last block reduces ebuf in PARALLEL (fixed tree)
    if (t == 0) {
        ebuf[bid] = ssum;
        __threadfence();
        unsigned old = atomicAdd(counter, 1u);
        islast = (old == (unsigned)gridDim.x - 1u) ? 1 : 0;
    }
    __syncthreads();
    if (islast) {
        __threadfence();
        float v = (t < NBLK_MLP) ? ebuf[t] : 0.f;
#pragma unroll
        for (int off = 32; off; off >>= 1) v += __shfl_down(v, off);
        if (lane == 0) wred[wv] = v;
        __syncthreads();
        if (t == 0) {
            float tot = 0.f;
#pragma unroll
            for (int i = 0; i < 8; ++i) tot += wred[i];
            out[0] = tot;
        }
    }
}

extern "C" void kernel_launch(void* const* d_in, const int* in_sizes, int n_in,
                              void* d_out, int out_size, void* d_ws, size_t ws_size,
                              hipStream_t stream)
{
    const int*   species = (const int*)d_in[0];
    const float* coords  = (const float*)d_in[1];
    const float* W0 = (const float*)d_in[2];
    const float* b0 = (const float*)d_in[3];
    const float* W1 = (const float*)d_in[4];
    const float* b1 = (const float*)d_in[5];
    const float* W2 = (const float*)d_in[6];
    const float* b2 = (const float*)d_in[7];
    const float* W3 = (const float*)d_in[8];
    const float* b3 = (const float*)d_in[9];
    float* out = (float*)d_out;

    // Workspace layout: total 2,069,632 B (< 2 MiB)
    char* ws = (char*)d_ws;
    int*      seg     = (int*)(ws);                   // [0, 32)
    unsigned* counter = (unsigned*)(ws + 48);         // [48, 52)
    float*    ebuf    = (float*)(ws + 64);            // 135 f32 -> ends 604
    float*    cvec    = (float*)(ws + 640);           // 14 f32 ladder constants
    float4*   cxyz    = (float4*)(ws + 1152);         // 2048 float4 (32 KB)
    ushort_t* aevb    = (ushort_t*)(ws + 33920);      // 2048*112 bf16 (448 KB)
    ushort_t* wr0     = (ushort_t*)(ws + 492672);     // 229376 bf16
    ushort_t* wr1     = (ushort_t*)(ws + 951424);     // 344064 bf16
    ushort_t* wr2     = (ushort_t*)(ws + 1639552);    // 215040 bf16

    hipLaunchKernelGGL(sort_kernel, dim3(1), dim3(1024), 0, stream,
                       species, coords, seg, cxyz, counter, cvec);
    hipLaunchKernelGGL(aev_kernel, dim3(AEV_BLKS), dim3(256), 0, stream,
                       seg, cxyz, cvec, aevb, W0, W1, W2, wr0, wr1, wr2);
    hipLaunchKernelGGL(mlp_kernel, dim3(NBLK_MLP), dim3(512), 0, stream,
                       seg, aevb, wr0, wr1, wr2, b0, b1, b2, W3, b3,
                       ebuf, counter, out);
}

// Round 10
// 31.787 us; speedup vs baseline: 4.4226x; 1.0700x over previous
//
#include <hip/hip_runtime.h>
#include <hip/hip_fp16.h>
#include <math.h>

#define N_ATOMS 2048
#define NSP 7
#define AEVD 112      // real radial features; padded to 128 (K-tile) only in LDS
#define MTILE 16      // atoms per MLP block (full 16-row M-tile)
#define NBLK_MLP 135  // max tiles: 2048/16 + 7 slack
#define AEV_TASKS (N_ATOMS * NSP)           // (atom, species) wave-tasks, 16 shells each
#define AEV_BLKS (AEV_TASKS / 4)            // 3584 blocks of 4 waves

typedef __attribute__((ext_vector_type(8))) short short8;
typedef __attribute__((ext_vector_type(4))) float f32x4;
typedef __attribute__((ext_vector_type(2))) float f32x2;
typedef unsigned short ushort_t;
typedef unsigned long long u64;

// ---- guaranteed-native transcendentals (single HW instruction) ----
#if !__has_builtin(__builtin_amdgcn_exp2f)
extern "C" __device__ float __ocml_native_exp2_f32(float);
#endif
#if !__has_builtin(__builtin_amdgcn_cosf)
extern "C" __device__ float __ocml_native_cos_f32(float);
#endif
#if !__has_builtin(__builtin_amdgcn_sqrtf)
extern "C" __device__ float __ocml_native_sqrt_f32(float);
#endif

__device__ __forceinline__ float nexp2(float x) {       // 2^x  (v_exp_f32)
#if __has_builtin(__builtin_amdgcn_exp2f)
    return __builtin_amdgcn_exp2f(x);
#else
    return __ocml_native_exp2_f32(x);
#endif
}
__device__ __forceinline__ float ncos_rev(float x) {    // cos(2*pi*x) (v_cos_f32)
#if __has_builtin(__builtin_amdgcn_cosf)
    return __builtin_amdgcn_cosf(x);
#else
    return __ocml_native_cos_f32(x * 6.2831853071795865f);
#endif
}
__device__ __forceinline__ float nsqrt(float x) {       // sqrt(x) (v_sqrt_f32)
#if __has_builtin(__builtin_amdgcn_sqrtf)
    return __builtin_amdgcn_sqrtf(x);
#else
    return __ocml_native_sqrt_f32(x);
#endif
}

// even-shell mus (ladder order; SHFR[2j] = mu_e[j])
__device__ __constant__ float c_mue[8] = {0.9f, 1.43f, 1.96f, 2.49f,
                                          3.02f, 3.55f, 4.08f, 4.61f};

#define CS_LOG2E  (-23.083120654223414f)   // -16*log2(e)
#define CB_LOG2E  ( 46.166241308446828f)   // +32*log2(e)
#define EA_COEF   ( 12.003222740196175f)   // CB_LOG2E * 0.26 (even->odd shell step)
#define EB_COEF   ( 24.468107893476819f)   // CB_LOG2E * 0.53 (even->even shell step)

__device__ __forceinline__ float celu01(float x) {
    return x > 0.f ? x : 0.1f * (nexp2(x * 14.426950f) - 1.f);
}

__device__ __forceinline__ ushort_t f2bf(float v) {   // RNE fp32->bf16
    unsigned u = __float_as_uint(v);
    u += 0x7fffu + ((u >> 16) & 1u);
    return (ushort_t)(u >> 16);
}

__device__ __forceinline__ unsigned pkadd16(unsigned a, unsigned b) {  // v_pk_add_f16
    __half2 x, y;
    __builtin_memcpy(&x, &a, 4);
    __builtin_memcpy(&y, &b, 4);
    __half2 r = __hadd2(x, y);
    unsigned u;
    __builtin_memcpy(&u, &r, 4);
    return u;
}

#define PREP_G0 28672   // 7*16*4*64
#define PREP_G1 43008   // 7*12*8*64
#define PREP_G2 26880   // 7*10*6*64
#define PREP_GT (PREP_G0 + PREP_G1 + PREP_G2)   // 98560 <= 97*1024

// repack one fragment unit (store offset uses branch-LOCAL g — R2 lesson)
__device__ __forceinline__ void repack_unit(
    int g, const float* __restrict__ W0, const float* __restrict__ W1,
    const float* __restrict__ W2,
    ushort_t* __restrict__ wr0, ushort_t* __restrict__ wr1,
    ushort_t* __restrict__ wr2)
{
    const float* W; ushort_t* dst; int NT, KS, KREAL, KIN, NOUT;
    if (g < PREP_G0)                 { W = W0; dst = wr0; NT = 16; KS = 4; KREAL = 112; KIN = 1008; NOUT = 256; }
    else if (g < PREP_G0 + PREP_G1)  { g -= PREP_G0; W = W1; dst = wr1; NT = 12; KS = 8; KREAL = 256; KIN = 256; NOUT = 192; }
    else                             { g -= PREP_G0 + PREP_G1; W = W2; dst = wr2; NT = 10; KS = 6; KREAL = 192; KIN = 192; NOUT = 160; }
    int L = g & 63, rest = g >> 6;
    int ks = rest % KS; rest /= KS;
    int nt = rest % NT; int s = rest / NT;
    int n = nt * 16 + (L & 15);
    int k0 = ks * 32 + ((L >> 4) << 3);
    const float* src = W + (size_t)s * KIN * NOUT + n;
    short8 v8;
#pragma unroll
    for (int j = 0; j < 8; ++j) {
        int k = k0 + j;
        float v = (k < KREAL) ? src[(size_t)k * NOUT] : 0.f;
        v8[j] = (short)f2bf(v);
    }
    *(short8*)(dst + (size_t)g * 8) = v8;   // LOCAL g (fragment-linear)
}

// ---------------------------------------------------------------------------
// Kernel 1 (fused, R7 structure): block 0 = counting sort + ladder consts;
// blocks 1..97 = weight repack (overlaps the sort — R9 showed this overlap
// is worth ~2 µs).  R10 sort-block micro-cuts: (a) packed u64 7-species
// scan (7x9-bit fields, max 128/field -> no carry); (b) direct scatter of
// cxyz from staged cloc (kills sortedL round-trip + one barrier + gather).
// ---------------------------------------------------------------------------
__global__ __launch_bounds__(1024) void sortprep_kernel(
    const int* __restrict__ species, const float* __restrict__ coords,
    int* __restrict__ seg, float4* __restrict__ cxyz,
    unsigned* __restrict__ counter, float* __restrict__ cvec,
    const float* __restrict__ W0, const float* __restrict__ W1,
    const float* __restrict__ W2,
    ushort_t* __restrict__ wr0, ushort_t* __restrict__ wr1,
    ushort_t* __restrict__ wr2)
{
    __shared__ int wsum[16][NSP];   // per-wave per-species counts
    __shared__ int wpre[16][NSP];   // inclusive prefix over waves
    __shared__ float cloc[3 * N_ATOMS];   // 24 KB staged coords
    int t = threadIdx.x;

    if (blockIdx.x != 0) {
        int g = (blockIdx.x - 1) * 1024 + t;
        if (g < PREP_GT) repack_unit(g, W0, W1, W2, wr0, wr1, wr2);
        return;
    }

    // ---- coalesced coords -> LDS (latency hides under the scans) ----
#pragma unroll
    for (int i = 0; i < 6; ++i) cloc[t + i * 1024] = coords[t + i * 1024];

    // ladder constants: cvec[0..5] = cke pairs {lo,hi} x3; cvec[6..13] = cko
    if (t < 14) {
        float v;
        if (t < 6) {
            int i = t >> 1, hi = t & 1;
            float b = c_mue[i + (hi ? 4 : 0)];
            float a = c_mue[i + (hi ? 5 : 1)];
            v = nexp2(CS_LOG2E * (a * a - b * b));
        } else {
            int j = t - 6;
            float me = c_mue[j], mo = me + 0.26f;
            v = nexp2(CS_LOG2E * (mo * mo - me * me));
        }
        cvec[t] = v;
    }

    int lane = t & 63, wv = t >> 6;
    if (t == 0) counter[0] = 0u;

    int s0 = species[2 * t], s1 = species[2 * t + 1];

    // packed intra-wave scan: one u64 scan instead of 7 scalar scans
    u64 myc = (1ull << (9 * s0)) + (1ull << (9 * s1));
    u64 pc = myc;
    for (int d = 1; d < 64; d <<= 1) {
        u64 o = __shfl_up(pc, d);
        if (lane >= d) pc += o;
    }
    if (lane == 63) {
#pragma unroll
        for (int s = 0; s < NSP; ++s)
            wsum[wv][s] = (int)((pc >> (9 * s)) & 511);
    }
    __syncthreads();

    // cross-wave scan: 112 lanes (2 waves), width-16 shfl scan per species
    // (unpacked: species totals up to 2048 would overflow 9-bit fields)
    if (t < 112) {
        int s = t >> 4;
        int w = t & 15;
        int v = wsum[w][s];
        for (int d = 1; d < 16; d <<= 1) {
            int o = __shfl_up(v, d, 16);
            if ((t & 15) >= d) v += o;
        }
        wpre[w][s] = v;                     // inclusive over waves 0..w
    }
    __syncthreads();

    // positions for this thread's 2 atoms (stable: atom 2t before 2t+1)
    u64 excl = pc - myc;                    // field-wise exclusive lane prefix
    int run = 0;
    int p0 = 0, p1 = 0;
#pragma unroll
    for (int s = 0; s < NSP; ++s) {
        int tot = wpre[15][s];
        int woff = wpre[wv][s] - wsum[wv][s];          // exclusive wave prefix
        int e = (int)((excl >> (9 * s)) & 511);
        int base = run + woff + e;
        if (s0 == s) { p0 = base; base++; }
        if (s1 == s) { p1 = base; }
        if (t == 0) seg[s] = run;
        run += tot;
    }
    if (t == 0) seg[NSP] = run;

    // direct scatter (cloc staging completed before the first barrier)
    cxyz[p0] = make_float4(cloc[6 * t + 0], cloc[6 * t + 1], cloc[6 * t + 2], 0.f);
    cxyz[p1] = make_float4(cloc[6 * t + 3], cloc[6 * t + 4], cloc[6 * t + 5], 0.f);
}

// ---------------------------------------------------------------------------
// Kernel 2: radial AEV, one wave-task = (atom, species), all 16 shells.
// Packed-f32 two-anchor ladder; cvec constants; fold-reduction (34 ops).
// (R7-exact — control)
// ---------------------------------------------------------------------------
__global__ __launch_bounds__(256) void aev_kernel(
    const int* __restrict__ seg, const float4* __restrict__ cxyz,
    const float* __restrict__ cvec, ushort_t* __restrict__ aevb)
{
    int t = threadIdx.x;
    int jl = t & 63;
    int gid = blockIdx.x * 4 + (t >> 6);   // 0 .. 14335
    int atom = gid / 7;                    // magic-mul const div
    int s = gid - atom * 7;

    const float BE_A0 = CB_LOG2E * 0.9f;
    const float GE_A0 = CS_LOG2E * (0.9f * 0.9f);
    const float BE_A1 = CB_LOG2E * 3.02f;
    const float GE_A1 = CS_LOG2E * (3.02f * 3.02f);

    float4 ci = cxyz[atom];
    float xi = ci.x, yi = ci.y, zi = ci.z;
    int pb = seg[s], pe = seg[s + 1];

    // ladder constants (uniform -> scalar loads; latency overlaps seg/cxyz)
    f32x2 cke0 = (f32x2){cvec[0], cvec[1]};
    f32x2 cke1 = (f32x2){cvec[2], cvec[3]};
    f32x2 cke2 = (f32x2){cvec[4], cvec[5]};
    float cko[8];
#pragma unroll
    for (int j = 0; j < 8; ++j) cko[j] = cvec[6 + j];

    f32x2 accE[4], accO[4];
#pragma unroll
    for (int i = 0; i < 4; ++i) {
        accE[i] = (f32x2){0.f, 0.f};
        accO[i] = (f32x2){0.f, 0.f};
    }

    const float4* pj = cxyz + pb + jl;
    for (int n = pe - pb - jl; n > 0; n -= 64, pj += 64) {
        float4 cj = *pj;                           // L1-resident (32KB total)
        float dx = cj.x - xi, dy = cj.y - yi, dz = cj.z - zi;
        float sq = fmaf(dx, dx, fmaf(dy, dy, dz * dz));
        float d  = nsqrt(sq);
        float dc = fminf(d, 5.2f);                 // clamp: keeps eb/ea finite; fc(5.2)=0
        float fc = fmaf(0.5f, ncos_rev(dc * 0.09615384615f), 0.5f);
        float uc = CS_LOG2E * sq;
        float ea = nexp2(dc * EA_COEF);            // even->odd ratio (shared)
        float fe = ea * fc;
        float ebv = nexp2(dc * EB_COEF);           // even->even ratio (shared)
        f32x2 eb2 = (f32x2){ebv, ebv};
        f32x2 fc2 = (f32x2){fc, fc};
        f32x2 fe2 = (f32x2){fe, fe};
        f32x2 ek0 = eb2 * cke0;
        f32x2 ek1 = eb2 * cke1;
        f32x2 ek2 = eb2 * cke2;
        f32x2 ve = (f32x2){ nexp2(fmaf(dc, BE_A0, uc) + GE_A0),
                            nexp2(fmaf(dc, BE_A1, uc) + GE_A1) };
        accE[0] = ve * fc2 + accE[0];  accO[0] = ve * fe2 + accO[0];
        ve = ve * ek0;
        accE[1] = ve * fc2 + accE[1];  accO[1] = ve * fe2 + accO[1];
        ve = ve * ek1;
        accE[2] = ve * fc2 + accE[2];  accO[2] = ve * fe2 + accO[2];
        ve = ve * ek2;
        accE[3] = ve * fc2 + accE[3];  accO[3] = ve * fe2 + accO[3];
    }

    // subtract the self-pair: exact replica of the in-loop ladder at sq=0
    if (pb <= atom && atom < pe && ((atom - pb) & 63) == jl) {
        f32x2 ve = (f32x2){ nexp2(GE_A0), nexp2(GE_A1) };
        accE[0] -= ve;  accO[0] -= ve;
        ve = ve * cke0;
        accE[1] -= ve;  accO[1] -= ve;
        ve = ve * cke1;
        accE[2] -= ve;  accO[2] -= ve;
        ve = ve * cke2;
        accE[3] -= ve;  accO[3] -= ve;
    }

    // pack to half2 words: hu[j] = {E[j], O[j]*cko[j]} (shells 2j, 2j+1)
    unsigned hu[8];
#pragma unroll
    for (int j = 0; j < 8; ++j) {
        float E = (j < 4) ? accE[j][0] : accE[j - 4][1];
        float O = ((j < 4) ? accO[j][0] : accO[j - 4][1]) * cko[j];
        __half2 hh = __floats2half2_rn(E, O);
        __builtin_memcpy(&hu[j], &hh, 4);
    }

    // ---- fold-reduction: 34 ops vs 96 for the full butterfly ----
    bool hi5 = (jl & 32) != 0;
#pragma unroll
    for (int j = 0; j < 4; ++j) {
        unsigned snd = hi5 ? hu[j] : hu[j + 4];
        unsigned rcv = (unsigned)__shfl_xor((int)snd, 32);
        unsigned kp  = hi5 ? hu[j + 4] : hu[j];
        hu[j] = pkadd16(kp, rcv);
    }
    bool hi4 = (jl & 16) != 0;
#pragma unroll
    for (int j = 0; j < 2; ++j) {
        unsigned snd = hi4 ? hu[j] : hu[j + 2];
        unsigned rcv = (unsigned)__shfl_xor((int)snd, 16);
        unsigned kp  = hi4 ? hu[j + 2] : hu[j];
        hu[j] = pkadd16(kp, rcv);
    }
    bool hi3 = (jl & 8) != 0;
    {
        unsigned snd = hi3 ? hu[0] : hu[1];
        unsigned rcv = (unsigned)__shfl_xor((int)snd, 8);
        unsigned kp  = hi3 ? hu[1] : hu[0];
        hu[0] = pkadd16(kp, rcv);
    }
#pragma unroll
    for (int off = 4; off; off >>= 1)
        hu[0] = pkadd16(hu[0], (unsigned)__shfl_xor((int)hu[0], off));

    // word w = (jl>>3)&7 lives on lanes 8w..8w+7; lane 8w writes shells (2w,2w+1)
    if ((jl & 7) == 0) {
        int w = jl >> 3;
        __half2 hv;
        __builtin_memcpy(&hv, &hu[0], 4);
        float2 f = __half22float2(hv);
        unsigned pk = (unsigned)f2bf(f.x) | ((unsigned)f2bf(f.y) << 16);
        *(unsigned*)(aevb + (size_t)atom * AEVD + s * 16 + 2 * w) = pk;
    }
}

// ---------------------------------------------------------------------------
// Kernel 3: MFMA MLP — 512 threads, 8 waves split the N-tiles.  Next-layer
// weight fragments prefetched BEFORE the current layer's MFMAs; L0 weights
// issued before the staging sync; parallel ered/ebuf reductions. (R7-exact)
// ---------------------------------------------------------------------------

template<int KSTEPS, int NT>
__device__ __forceinline__ void load_wf(const ushort_t* __restrict__ wrep,
                                        short8 (&wf)[(NT + 7) / 8][KSTEPS],
                                        int lane, int wv)
{
    constexpr int MAXNT = (NT + 7) / 8;
    const int myNT = (NT - wv + 7) / 8;
#pragma unroll
    for (int i = 0; i < MAXNT; ++i) {
        if (i < myNT) {
            int nt = wv + i * 8;
            const ushort_t* wb = wrep + ((size_t)nt * KSTEPS) * 512 + lane * 8;
#pragma unroll
            for (int ks = 0; ks < KSTEPS; ++ks)
                wf[i][ks] = *(const short8*)(wb + ks * 512);
        }
    }
}

template<int KSTEPS, int NT, int SIN, int NOUT, bool OUTF32, int NKSTEPS, int NNT, bool PREF>
__device__ __forceinline__ void compute_layer8(
    const float* __restrict__ bias,
    const ushort_t* Ain,                 // LDS bf16 [16][SIN], swizzled
    ushort_t* Aout,                      // LDS bf16 [16][NOUT], swizzled
    float* Fout,                         // LDS fp32 [16][NOUT] (if OUTF32)
    short8 (&wf)[(NT + 7) / 8][KSTEPS],  // preloaded B fragments for THIS layer
    const ushort_t* __restrict__ nwrep,  // next-layer weight base
    short8 (&nwf)[(NNT + 7) / 8][NKSTEPS],
    int lane, int wv)
{
    constexpr int MAXNT = (NT + 7) / 8;
    const int myNT = (NT - wv + 7) / 8;

    if constexpr (PREF) {
        load_wf<NKSTEPS, NNT>(nwrep, nwf, lane, wv);
    }

    short8 af[KSTEPS];
    {
        int m = lane & 15;
        int kb = (lane >> 4) << 3;
        unsigned base = (unsigned)(m * (SIN * 2));
        unsigned swz = (unsigned)((m & 7) << 4);
#pragma unroll
        for (int ks = 0; ks < KSTEPS; ++ks) {
            unsigned addr = (base + (unsigned)((ks * 32 + kb) * 2)) ^ swz;
            af[ks] = *(const short8*)((const char*)Ain + addr);
        }
    }
    f32x4 acc[MAXNT];
#pragma unroll
    for (int i = 0; i < MAXNT; ++i) {
        acc[i] = (f32x4){0.f, 0.f, 0.f, 0.f};
        if (i < myNT) {
#pragma unroll
            for (int ks = 0; ks < KSTEPS; ++ks)
                acc[i] = __builtin_amdgcn_mfma_f32_16x16x32_bf16(af[ks], wf[i][ks], acc[i], 0, 0, 0);
        }
    }
#pragma unroll
    for (int i = 0; i < MAXNT; ++i) {
        if (i < myNT) {
            int nt = wv + i * 8;
            int n = nt * 16 + (lane & 15);
            float bb = bias[n];
#pragma unroll
            for (int r = 0; r < 4; ++r) {
                int m = ((lane >> 4) << 2) + r;
                float v = celu01(acc[i][r] + bb);
                if (OUTF32) {
                    Fout[m * NOUT + n] = v;
                } else {
                    unsigned addr = (unsigned)(m * (NOUT * 2) + n * 2) ^ ((unsigned)((m & 7) << 4));
                    *(ushort_t*)((char*)Aout + addr) = f2bf(v);
                }
            }
        }
    }
    __syncthreads();
}

__global__ __launch_bounds__(512, 1) void mlp_kernel(
    const int* __restrict__ seg, const ushort_t* __restrict__ aevb,
    const ushort_t* __restrict__ wr0, const ushort_t* __restrict__ wr1,
    const ushort_t* __restrict__ wr2,
    const float* __restrict__ b0, const float* __restrict__ b1,
    const float* __restrict__ b2,
    const float* __restrict__ W3, const float* __restrict__ b3,
    float* __restrict__ ebuf, unsigned* __restrict__ counter,
    float* __restrict__ out)
{
    __shared__ __align__(16) ushort_t bufA[16 * 256];
    __shared__ __align__(16) ushort_t bufB[16 * 256];
    __shared__ __align__(16) float h2f[16 * 160];
    __shared__ float ered[MTILE];
    __shared__ float wred[8];
    __shared__ int islast;

    int t = threadIdx.x;
    int lane = t & 63, wv = t >> 6;
    int bid = blockIdx.x;

    int sfound = -1, tile = 0, segbase = 0, na = 0;
    int t0 = 0;
    for (int s = 0; s < NSP; ++s) {
        int beg = seg[s], end = seg[s + 1];
        int n = end - beg;
        int nt = (n + MTILE - 1) >> 4;
        if (sfound < 0 && bid < t0 + nt) {
            sfound = s; tile = bid - t0; segbase = beg;
            int rem = n - tile * MTILE;
            na = rem < MTILE ? rem : MTILE;
        }
        t0 += nt;
    }

    float ssum = 0.f;
    if (sfound >= 0) {
        int s = sfound;
        int row0 = segbase + tile * MTILE;

        float w3v[5];
        {
            const float* w3 = W3 + (size_t)s * 160 + (t & 31);
#pragma unroll
            for (int j = 0; j < 5; ++j) w3v[j] = w3[j * 32];
        }

        short8 wf0[2][4];
        short8 wf1[2][8];
        short8 wf2[2][6];
        short8 wfd[1][1];
        load_wf<4, 16>(wr0 + (size_t)s * 16 * 4 * 512, wf0, lane, wv);

        if (t < 256) {
            int m = t >> 4, piece = t & 15;
            short8 v = (short8){0,0,0,0,0,0,0,0};
            if (m < na && piece < 14)
                v = *(const short8*)(aevb + (size_t)(row0 + m) * AEVD + piece * 8);
            unsigned addr = (unsigned)(m * 256 + piece * 16) ^ ((unsigned)((m & 7) << 4));
            *(short8*)((char*)bufA + addr) = v;
        }
        __syncthreads();

        compute_layer8<4, 16, 128, 256, false, 8, 12, true>(
            b0 + s * 256, bufA, bufB, nullptr, wf0,
            wr1 + (size_t)s * 12 * 8 * 512, wf1, lane, wv);
        compute_layer8<8, 12, 256, 192, false, 6, 10, true>(
            b1 + s * 192, bufB, bufA, nullptr, wf1,
            wr2 + (size_t)s * 10 * 6 * 512, wf2, lane, wv);
        compute_layer8<6, 10, 192, 160, true, 1, 1, false>(
            b2 + s * 160, bufA, nullptr, h2f, wf2,
            nullptr, wfd, lane, wv);

        {
            int a = t >> 5, l = t & 31;
            float part = 0.f;
#pragma unroll
            for (int j = 0; j < 5; ++j) part = fmaf(h2f[a * 160 + l + j * 32], w3v[j], part);
            for (int off = 16; off; off >>= 1) part += __shfl_down(part, off, 32);
            if (l == 0) ered[a] = part;
        }
        __syncthreads();
        if (t < 16) {
            float v = (t < na) ? ered[t] : 0.f;
#pragma unroll
            for (int off = 8; off; off >>= 1) v += __shfl_down(v, off, 16);
            if (t == 0) ssum = v + (float)na * b3[s];
        }
    }

    // completion protocol: last block reduces ebuf in PARALLEL (fixed tree)
    if (t == 0) {
        ebuf[bid] = ssum;
        __threadfence();
        unsigned old = atomicAdd(counter, 1u);
        islast = (old == (unsigned)gridDim.x - 1u) ? 1 : 0;
    }
    __syncthreads();
    if (islast) {
        __threadfence();
        float v = (t < NBLK_MLP) ? ebuf[t] : 0.f;
#pragma unroll
        for (int off = 32; off; off >>= 1) v += __shfl_down(v, off);
        if (lane == 0) wred[wv] = v;
        __syncthreads();
        if (t == 0) {
            float tot = 0.f;
#pragma unroll
            for (int i = 0; i < 8; ++i) tot += wred[i];
            out[0] = tot;
        }
    }
}

extern "C" void kernel_launch(void* const* d_in, const int* in_sizes, int n_in,
                              void* d_out, int out_size, void* d_ws, size_t ws_size,
                              hipStream_t stream)
{
    const int*   species = (const int*)d_in[0];
    const float* coords  = (const float*)d_in[1];
    const float* W0 = (const float*)d_in[2];
    const float* b0 = (const float*)d_in[3];
    const float* W1 = (const float*)d_in[4];
    const float* b1 = (const float*)d_in[5];
    const float* W2 = (const float*)d_in[6];
    const float* b2 = (const float*)d_in[7];
    const float* W3 = (const float*)d_in[8];
    const float* b3 = (const float*)d_in[9];
    float* out = (float*)d_out;

    // Workspace layout: total 2,069,632 B (< 2 MiB)
    char* ws = (char*)d_ws;
    int*      seg     = (int*)(ws);                   // [0, 32)
    unsigned* counter = (unsigned*)(ws + 48);         // [48, 52)
    float*    ebuf    = (float*)(ws + 64);            // 135 f32 -> ends 604
    float*    cvec    = (float*)(ws + 640);           // 14 f32 ladder constants
    float4*   cxyz    = (float4*)(ws + 1152);         // 2048 float4 (32 KB)
    ushort_t* aevb    = (ushort_t*)(ws + 33920);      // 2048*112 bf16 (448 KB)
    ushort_t* wr0     = (ushort_t*)(ws + 492672);     // 229376 bf16
    ushort_t* wr1     = (ushort_t*)(ws + 951424);     // 344064 bf16
    ushort_t* wr2     = (ushort_t*)(ws + 1639552);    // 215040 bf16

    hipLaunchKernelGGL(sortprep_kernel, dim3(98), dim3(1024), 0, stream,
                       species, coords, seg, cxyz, counter, cvec,
                       W0, W1, W2, wr0, wr1, wr2);
    hipLaunchKernelGGL(aev_kernel, dim3(AEV_BLKS), dim3(256), 0, stream,
                       seg, cxyz, cvec, aevb);
    hipLaunchKernelGGL(mlp_kernel, dim3(NBLK_MLP), dim3(512), 0, stream,
                       seg, aevb, wr0, wr1, wr2, b0, b1, b2, W3, b3,
                       ebuf, counter, out);
}